// Round 1
// baseline (18319.839 us; speedup 1.0000x reference)
//
#include <hip/hip_runtime.h>
#include <hip/hip_cooperative_groups.h>

// ---------------- problem constants ----------------
#define T_DIM 512
#define B_DIM 256
#define D_DIM 512
#define H_DIM 512
#define TB_DIM (T_DIM * B_DIM)   // 131072 (GEMM M)
#define NG_DIM (4 * H_DIM)       // 2048   (GEMM N, 4 gates concat)

typedef _Float16 half_t;
typedef _Float16 v8h __attribute__((ext_vector_type(8)));
typedef _Float16 v4h __attribute__((ext_vector_type(4)));
typedef _Float16 v2h __attribute__((ext_vector_type(2)));
typedef float v4f __attribute__((ext_vector_type(4)));
typedef float v2f __attribute__((ext_vector_type(2)));

namespace cg = cooperative_groups;

// async global->LDS, 16B per lane (global_load_lds_dwordx4)
__device__ __forceinline__ void async_ld16(void* lds, const void* gsrc) {
  __builtin_amdgcn_global_load_lds((__attribute__((address_space(1))) void*)gsrc,
                                   (__attribute__((address_space(3))) void*)lds,
                                   16, 0, 0);
}

__device__ __forceinline__ float sigmoid_f(float x) {
  return 1.0f / (1.0f + __expf(-x));
}
__device__ __forceinline__ float tanh_f(float x) {
  // 1 - 2/(e^{2x}+1); overflow-safe (exp->inf => 1, exp->0 => -1)
  float e = __expf(2.0f * x);
  return 1.0f - 2.0f / (e + 1.0f);
}

// ---------------- converts ----------------
__global__ __launch_bounds__(256) void k_convX(const float4* __restrict__ X,
                                               v4h* __restrict__ Xh, int n4) {
  int i = blockIdx.x * 256 + threadIdx.x;
  if (i < n4) {
    float4 v = X[i];
    v4h o;
    o[0] = (half_t)v.x; o[1] = (half_t)v.y; o[2] = (half_t)v.z; o[3] = (half_t)v.w;
    Xh[i] = o;
  }
}

// builds Wcat16 [2048][512] (f,i,o,a concatenated) and Waa16 [512][512]
__global__ __launch_bounds__(256) void k_convW(const float4* __restrict__ wf,
                                               const float4* __restrict__ wi,
                                               const float4* __restrict__ wo,
                                               const float4* __restrict__ wa,
                                               const float4* __restrict__ waa,
                                               v4h* __restrict__ Wcat,
                                               v4h* __restrict__ Waa16) {
  int idx = blockIdx.x * 256 + threadIdx.x;   // over 5*65536 float4s
  int chunk = idx >> 16;
  int off = idx & 65535;
  const float4* src = (chunk == 0) ? wf : (chunk == 1) ? wi : (chunk == 2) ? wo
                      : (chunk == 3) ? wa : waa;
  float4 v = src[off];
  v4h o;
  o[0] = (half_t)v.x; o[1] = (half_t)v.y; o[2] = (half_t)v.z; o[3] = (half_t)v.w;
  if (chunk < 4) Wcat[chunk * 65536 + off] = o;
  else           Waa16[off] = o;
}

// bsum[col], col = g*512+j: g in {f,i,o}: b_g + b_a ; g==3 (a-gate): b_a
__global__ __launch_bounds__(256) void k_bias(const float* __restrict__ bf,
                                              const float* __restrict__ bi,
                                              const float* __restrict__ bo,
                                              const float* __restrict__ ba,
                                              float* __restrict__ bsum) {
  int i = blockIdx.x * 256 + threadIdx.x;  // 2048
  int g = i >> 9, j = i & 511;
  float v = ba[j];
  if (g == 0) v += bf[j];
  else if (g == 1) v += bi[j];
  else if (g == 2) v += bo[j];
  bsum[i] = v;
}

// ---------------- phase 1: gates = X @ Wcat^T + bsum (fp16 MFMA) ----------------
// 128x128 tile, BK=32, 4 waves each 64x64, m97-style staging. (unchanged)
__global__ __launch_bounds__(256) void k_gemm_gates(
    const half_t* __restrict__ A,    // Xh [TB][512]
    const half_t* __restrict__ Bm,   // Wcat [2048][512]
    const float* __restrict__ bsum,  // [2048]
    half_t* __restrict__ gates) {    // [4][TB][512]
  __shared__ __align__(16) half_t lA[128 * 32];
  __shared__ __align__(16) half_t lB[128 * 32];
  const int tid = threadIdx.x;
  const int l = tid & 63;
  const int w = tid >> 6;
  const int m0 = blockIdx.x * 128;
  const int n0 = blockIdx.y * 128;
  const int wm = (w >> 1) * 64;
  const int wn = (w & 1) * 64;
  const int lr = l & 15;
  const int lk = (l >> 4) * 8;

  v4f acc[4][4];
#pragma unroll
  for (int i = 0; i < 4; i++)
#pragma unroll
    for (int j = 0; j < 4; j++) acc[i][j] = (v4f){0.f, 0.f, 0.f, 0.f};

  const int row_in = tid >> 2;        // 0..63
  const int kc_in = (tid & 3) * 8;    // fp16 elems within BK

  for (int kt = 0; kt < 16; ++kt) {
    const int k0 = kt * 32;
    __syncthreads();
    async_ld16(&lA[tid * 8],        &A[(size_t)(m0 + row_in) * 512 + k0 + kc_in]);
    async_ld16(&lA[2048 + tid * 8], &A[(size_t)(m0 + 64 + row_in) * 512 + k0 + kc_in]);
    async_ld16(&lB[tid * 8],        &Bm[(size_t)(n0 + row_in) * 512 + k0 + kc_in]);
    async_ld16(&lB[2048 + tid * 8], &Bm[(size_t)(n0 + 64 + row_in) * 512 + k0 + kc_in]);
    __syncthreads();

    v8h af[4], bfr[4];
#pragma unroll
    for (int tm = 0; tm < 4; tm++)
      af[tm] = *(const v8h*)&lA[(wm + tm * 16 + lr) * 32 + lk];
#pragma unroll
    for (int tn = 0; tn < 4; tn++)
      bfr[tn] = *(const v8h*)&lB[(wn + tn * 16 + lr) * 32 + lk];
#pragma unroll
    for (int tm = 0; tm < 4; tm++)
#pragma unroll
      for (int tn = 0; tn < 4; tn++)
        acc[tm][tn] = __builtin_amdgcn_mfma_f32_16x16x32_f16(af[tm], bfr[tn],
                                                             acc[tm][tn], 0, 0, 0);
  }

  // epilogue: C/D layout col=lane&15, row=(lane>>4)*4+r  (m89/m91-verified)
#pragma unroll
  for (int tn = 0; tn < 4; tn++) {
    const int col = n0 + wn + tn * 16 + lr;   // virtual col in [0,2048)
    const int g = col >> 9;
    const int j = col & 511;
    const float bias = bsum[col];
    half_t* outg = gates + (size_t)g * TB_DIM * 512 + j;
#pragma unroll
    for (int tm = 0; tm < 4; tm++) {
      const int r0 = m0 + wm + tm * 16 + (l >> 4) * 4;
#pragma unroll
      for (int r = 0; r < 4; r++)
        outg[(size_t)(r0 + r) * 512] = (half_t)(acc[tm][tn][r] + bias);
    }
  }
}

// ---------------- phase 2: ALL steps in one persistent cooperative kernel ----
// grid = 256 blocks (1/CU), 256 threads (4 waves).
// block -> fixed output tile: b-rows [b0,b0+16), j-cols [j0,j0+32).
// Waa j-rows cached in LDS once. c-state in registers for all 512 steps.
// Per step: split-K MFMA (wave w covers K in [w*128,(w+1)*128)) -> LDS reduce
// -> fused gate elementwise -> store out fp32 + h fp16 -> grid.sync().
__global__ __launch_bounds__(256, 1) void k_steps(
    const half_t* __restrict__ Waa,    // [512][512] fp16
    const half_t* __restrict__ gates,  // [4][TB][512] fp16 (biases folded)
    float* __restrict__ out,           // [T][256][512] then h_n [256][512]
    half_t* __restrict__ hbuf) {       // 2 x [256][512] fp16
  cg::grid_group grid = cg::this_grid();

  // padded stride 520 halves (1040B): successive rows shift bank groups
  __shared__ __align__(16) half_t Wl[32][520];   // 33280 B
  __shared__ float red[4][16][33];               //  8448 B

  const int tid = threadIdx.x;
  const int l = tid & 63;
  const int w = tid >> 6;
  const int b0 = ((int)blockIdx.x >> 4) * 16;    // 16 M-tiles
  const int j0 = ((int)blockIdx.x & 15) * 32;    // 16 N-tiles
  const int lr = l & 15;
  const int lk8 = (l >> 4) * 8;

  // stage this block's 32 Waa rows into LDS (once, reused for 512 steps)
  for (int i = tid; i < 2048; i += 256) {        // 2048 v8h units
    const int row = i >> 6;                      // 64 v8h per row
    const int kc = (i & 63) * 8;
    *(v8h*)&Wl[row][kc] = *(const v8h*)&Waa[(size_t)(j0 + row) * 512 + kc];
  }
  __syncthreads();

  // per-thread persistent state: elems (row=tid>>4, cols (tid&15)*2 + {0,1})
  const int erow = tid >> 4;
  const int ecol = (tid & 15) * 2;
  const int gb = b0 + erow;                      // batch index
  const int gj = j0 + ecol;                      // hidden index
  float c0 = 0.f, c1 = 0.f;

  const size_t gstride = (size_t)TB_DIM * 512;

  for (int t = 0; t < T_DIM; ++t) {
    const half_t* __restrict__ hin = hbuf + (size_t)(t & 1) * (B_DIM * H_DIM);
    half_t* __restrict__ hout = hbuf + (size_t)((t + 1) & 1) * (B_DIM * H_DIM);

    // gates prefetch: independent of h -> HBM latency hides under MFMA phase
    const size_t gi = ((size_t)t * B_DIM + gb) * 512 + gj;
    const v2h pf = *(const v2h*)&gates[gi];
    const v2h pi = *(const v2h*)&gates[gstride + gi];
    const v2h po = *(const v2h*)&gates[2 * gstride + gi];
    const v2h pa = *(const v2h*)&gates[3 * gstride + gi];

    // ---- split-K GEMM partial: a = h_prev @ Waa^T ----
    v4f acc0 = (v4f){0.f, 0.f, 0.f, 0.f};
    v4f acc1 = (v4f){0.f, 0.f, 0.f, 0.f};
    if (t > 0) {                                  // h0 == 0 -> a == 0
#pragma unroll
      for (int kc = 0; kc < 4; ++kc) {
        const int k = w * 128 + kc * 32 + lk8;
        const v8h av = *(const v8h*)&hin[(size_t)(b0 + lr) * 512 + k];
        const v8h w0 = *(const v8h*)&Wl[lr][k];
        const v8h w1 = *(const v8h*)&Wl[16 + lr][k];
        acc0 = __builtin_amdgcn_mfma_f32_16x16x32_f16(av, w0, acc0, 0, 0, 0);
        acc1 = __builtin_amdgcn_mfma_f32_16x16x32_f16(av, w1, acc1, 0, 0, 0);
      }
    }
    // write partials: D layout col=lane&15, row=(lane>>4)*4+r
#pragma unroll
    for (int r = 0; r < 4; ++r) {
      red[w][(l >> 4) * 4 + r][lr] = acc0[r];
      red[w][(l >> 4) * 4 + r][16 + lr] = acc1[r];
    }
    __syncthreads();

    const float a0 = red[0][erow][ecol] + red[1][erow][ecol] +
                     red[2][erow][ecol] + red[3][erow][ecol];
    const float a1 = red[0][erow][ecol + 1] + red[1][erow][ecol + 1] +
                     red[2][erow][ecol + 1] + red[3][erow][ecol + 1];

    // ---- fused gate elementwise (c persistent in registers) ----
    {
      const float ft = sigmoid_f((float)pf[0] + a0);
      const float it = sigmoid_f((float)pi[0] + a0);
      const float ot = sigmoid_f((float)po[0] + a0);
      const float gg = tanh_f((float)pa[0] + a0);
      c0 = ft * c0 + it * gg;
      const float h0v = ot * tanh_f(c0);

      const float ft1 = sigmoid_f((float)pf[1] + a1);
      const float it1 = sigmoid_f((float)pi[1] + a1);
      const float ot1 = sigmoid_f((float)po[1] + a1);
      const float gg1 = tanh_f((float)pa[1] + a1);
      c1 = ft1 * c1 + it1 * gg1;
      const float h1v = ot1 * tanh_f(c1);

      v2f ov; ov[0] = h0v; ov[1] = h1v;
      *(v2f*)&out[(size_t)t * (B_DIM * H_DIM) + (size_t)gb * 512 + gj] = ov;
      v2h hv; hv[0] = (half_t)h0v; hv[1] = (half_t)h1v;
      *(v2h*)&hout[(size_t)gb * 512 + gj] = hv;
      if (t == T_DIM - 1) {
        *(v2f*)&out[(size_t)T_DIM * (B_DIM * H_DIM) + (size_t)gb * 512 + gj] = ov;
      }
    }

    grid.sync();   // orders hout(t) before hin reads(t+1); protects red reuse
  }
}

// ---------------- host ----------------
extern "C" void kernel_launch(void* const* d_in, const int* in_sizes, int n_in,
                              void* d_out, int out_size, void* d_ws, size_t ws_size,
                              hipStream_t stream) {
  const float* X = (const float*)d_in[0];
  const float* Wf = (const float*)d_in[1];
  const float* Wi = (const float*)d_in[2];
  const float* Wo = (const float*)d_in[3];
  const float* Wa = (const float*)d_in[4];
  const float* Waa = (const float*)d_in[5];
  const float* bf = (const float*)d_in[6];
  const float* bi = (const float*)d_in[7];
  const float* bo = (const float*)d_in[8];
  const float* ba = (const float*)d_in[9];
  float* out = (float*)d_out;

  char* ws = (char*)d_ws;
  // workspace layout (bytes)
  half_t* Xh    = (half_t*)(ws + 0);           // 134217728  [TB][512] fp16
  half_t* gates = (half_t*)(ws + 134217728);   // 536870912  [4][TB][512] fp16
  half_t* Wcat  = (half_t*)(ws + 671088640);   // 2097152    [2048][512] fp16
  half_t* Waa16 = (half_t*)(ws + 673185792);   // 524288     [512][512] fp16
  float*  bsum  = (float*)(ws + 673710080);    // 8192       [2048]
  half_t* hbuf  = (half_t*)(ws + 673718272);   // 524288     2x[256][512] fp16
  // total: ~643 MB

  k_convX<<<65536, 256, 0, stream>>>((const float4*)X, (v4h*)Xh, 16777216);
  k_convW<<<1280, 256, 0, stream>>>((const float4*)Wf, (const float4*)Wi,
                                    (const float4*)Wo, (const float4*)Wa,
                                    (const float4*)Waa, (v4h*)Wcat, (v4h*)Waa16);
  k_bias<<<8, 256, 0, stream>>>(bf, bi, bo, ba, bsum);

  k_gemm_gates<<<dim3(TB_DIM / 128, NG_DIM / 128), 256, 0, stream>>>(Xh, Wcat, bsum,
                                                                     gates);

  // all 512 recurrent steps in one cooperative persistent kernel
  const half_t* kWaa = Waa16;
  const half_t* kGates = gates;
  float* kOut = out;
  half_t* kHbuf = hbuf;
  void* args[] = {(void*)&kWaa, (void*)&kGates, (void*)&kOut, (void*)&kHbuf};
  hipLaunchCooperativeKernel((void*)k_steps, dim3(256), dim3(256), args, 0, stream);
}

// Round 2
// 2587.159 us; speedup vs baseline: 7.0811x; 7.0811x over previous
//
#include <hip/hip_runtime.h>

// ---------------- problem constants ----------------
#define T_DIM 512
#define B_DIM 256
#define D_DIM 512
#define H_DIM 512
#define TB_DIM (T_DIM * B_DIM)   // 131072 (GEMM M)
#define NG_DIM (4 * H_DIM)       // 2048   (GEMM N, 4 gates concat)

typedef _Float16 half_t;
typedef _Float16 v8h __attribute__((ext_vector_type(8)));
typedef _Float16 v4h __attribute__((ext_vector_type(4)));
typedef _Float16 v2h __attribute__((ext_vector_type(2)));
typedef float v4f __attribute__((ext_vector_type(4)));
typedef float v2f __attribute__((ext_vector_type(2)));

// async global->LDS, 16B per lane (global_load_lds_dwordx4)
__device__ __forceinline__ void async_ld16(void* lds, const void* gsrc) {
  __builtin_amdgcn_global_load_lds((__attribute__((address_space(1))) void*)gsrc,
                                   (__attribute__((address_space(3))) void*)lds,
                                   16, 0, 0);
}

__device__ __forceinline__ float sigmoid_f(float x) {
  return 1.0f / (1.0f + __expf(-x));
}
__device__ __forceinline__ float tanh_f(float x) {
  // 1 - 2/(e^{2x}+1); overflow-safe (exp->inf => 1, exp->0 => -1)
  float e = __expf(2.0f * x);
  return 1.0f - 2.0f / (e + 1.0f);
}

// ---------------- converts ----------------
__global__ __launch_bounds__(256) void k_convX(const float4* __restrict__ X,
                                               v4h* __restrict__ Xh, int n4) {
  int i = blockIdx.x * 256 + threadIdx.x;
  if (i < n4) {
    float4 v = X[i];
    v4h o;
    o[0] = (half_t)v.x; o[1] = (half_t)v.y; o[2] = (half_t)v.z; o[3] = (half_t)v.w;
    Xh[i] = o;
  }
}

// builds Wcat16 [2048][512] (f,i,o,a concatenated) and Waa16 [512][512]
__global__ __launch_bounds__(256) void k_convW(const float4* __restrict__ wf,
                                               const float4* __restrict__ wi,
                                               const float4* __restrict__ wo,
                                               const float4* __restrict__ wa,
                                               const float4* __restrict__ waa,
                                               v4h* __restrict__ Wcat,
                                               v4h* __restrict__ Waa16) {
  int idx = blockIdx.x * 256 + threadIdx.x;   // over 5*65536 float4s
  int chunk = idx >> 16;
  int off = idx & 65535;
  const float4* src = (chunk == 0) ? wf : (chunk == 1) ? wi : (chunk == 2) ? wo
                      : (chunk == 3) ? wa : waa;
  float4 v = src[off];
  v4h o;
  o[0] = (half_t)v.x; o[1] = (half_t)v.y; o[2] = (half_t)v.z; o[3] = (half_t)v.w;
  if (chunk < 4) Wcat[chunk * 65536 + off] = o;
  else           Waa16[off] = o;
}

// bsum[col], col = g*512+j: g in {f,i,o}: b_g + b_a ; g==3 (a-gate): b_a
__global__ __launch_bounds__(256) void k_bias(const float* __restrict__ bf,
                                              const float* __restrict__ bi,
                                              const float* __restrict__ bo,
                                              const float* __restrict__ ba,
                                              float* __restrict__ bsum) {
  int i = blockIdx.x * 256 + threadIdx.x;  // 2048
  int g = i >> 9, j = i & 511;
  float v = ba[j];
  if (g == 0) v += bf[j];
  else if (g == 1) v += bi[j];
  else if (g == 2) v += bo[j];
  bsum[i] = v;
}

// ---------------- phase 1: gates = X @ Wcat^T + bsum (fp16 MFMA) ----------------
// 128x128 tile, BK=32, 4 waves each 64x64, m97-style staging. (unchanged)
__global__ __launch_bounds__(256) void k_gemm_gates(
    const half_t* __restrict__ A,    // Xh [TB][512]
    const half_t* __restrict__ Bm,   // Wcat [2048][512]
    const float* __restrict__ bsum,  // [2048]
    half_t* __restrict__ gates) {    // [4][TB][512]
  __shared__ __align__(16) half_t lA[128 * 32];
  __shared__ __align__(16) half_t lB[128 * 32];
  const int tid = threadIdx.x;
  const int l = tid & 63;
  const int w = tid >> 6;
  const int m0 = blockIdx.x * 128;
  const int n0 = blockIdx.y * 128;
  const int wm = (w >> 1) * 64;
  const int wn = (w & 1) * 64;
  const int lr = l & 15;
  const int lk = (l >> 4) * 8;

  v4f acc[4][4];
#pragma unroll
  for (int i = 0; i < 4; i++)
#pragma unroll
    for (int j = 0; j < 4; j++) acc[i][j] = (v4f){0.f, 0.f, 0.f, 0.f};

  const int row_in = tid >> 2;        // 0..63
  const int kc_in = (tid & 3) * 8;    // fp16 elems within BK

  for (int kt = 0; kt < 16; ++kt) {
    const int k0 = kt * 32;
    __syncthreads();
    async_ld16(&lA[tid * 8],        &A[(size_t)(m0 + row_in) * 512 + k0 + kc_in]);
    async_ld16(&lA[2048 + tid * 8], &A[(size_t)(m0 + 64 + row_in) * 512 + k0 + kc_in]);
    async_ld16(&lB[tid * 8],        &Bm[(size_t)(n0 + row_in) * 512 + k0 + kc_in]);
    async_ld16(&lB[2048 + tid * 8], &Bm[(size_t)(n0 + 64 + row_in) * 512 + k0 + kc_in]);
    __syncthreads();

    v8h af[4], bfr[4];
#pragma unroll
    for (int tm = 0; tm < 4; tm++)
      af[tm] = *(const v8h*)&lA[(wm + tm * 16 + lr) * 32 + lk];
#pragma unroll
    for (int tn = 0; tn < 4; tn++)
      bfr[tn] = *(const v8h*)&lB[(wn + tn * 16 + lr) * 32 + lk];
#pragma unroll
    for (int tm = 0; tm < 4; tm++)
#pragma unroll
      for (int tn = 0; tn < 4; tn++)
        acc[tm][tn] = __builtin_amdgcn_mfma_f32_16x16x32_f16(af[tm], bfr[tn],
                                                             acc[tm][tn], 0, 0, 0);
  }

  // epilogue: C/D layout col=lane&15, row=(lane>>4)*4+r  (m89/m91-verified)
#pragma unroll
  for (int tn = 0; tn < 4; tn++) {
    const int col = n0 + wn + tn * 16 + lr;   // virtual col in [0,2048)
    const int g = col >> 9;
    const int j = col & 511;
    const float bias = bsum[col];
    half_t* outg = gates + (size_t)g * TB_DIM * 512 + j;
#pragma unroll
    for (int tm = 0; tm < 4; tm++) {
      const int r0 = m0 + wm + tm * 16 + (l >> 4) * 4;
#pragma unroll
      for (int r = 0; r < 4; r++)
        outg[(size_t)(r0 + r) * 512] = (half_t)(acc[tm][tn][r] + bias);
    }
  }
}

// ---------------- phase 2: one persistent block per batch row ----------------
// Batch rows are INDEPENDENT (a[b,:] depends only on h[b,:]) -> no grid sync.
// 256 blocks (1/CU) x 256 threads (4 waves). Block b owns batch row b for all
// 512 steps. W_aa weight-stationary on-chip:
//   - LDS: j-tiles 0..8  (4 waves x 9 jt x 4 kc x 1KB = 144 KB)
//   - VGPRs: j-tiles 9..31 as pre-formatted MFMA B-fragments (368 regs/lane)
// Split-K across waves (wave w: k in [w*128,(w+1)*128)), LDS f32 reduce,
// fused gate elementwise, c in registers, h in a 1KB LDS buffer.
// Gates for step t+1 prefetched at top of step t (HBM latency hidden).
#define WLDS_JT 9
#define WREG_JT 23

__global__ __launch_bounds__(256, 1) void k_seq(
    const half_t* __restrict__ Waa,    // [512][512] fp16
    const half_t* __restrict__ gates,  // [4][TB][512] fp16 (biases folded)
    float* __restrict__ out) {         // [T][256][512] then h_n [256][512]
  __shared__ __align__(16) half_t Wl[4][WLDS_JT][4][512];  // 147456 B
  __shared__ __align__(16) float red[4][512];              //   8192 B
  __shared__ __align__(16) half_t hl[512];                 //   1024 B

  const int tid = threadIdx.x;
  const int l = tid & 63;
  const int w = tid >> 6;
  const int lr = l & 15;
  const int lk8 = (l >> 4) * 8;
  const int b = blockIdx.x;            // batch row
  const int ks = w * 128;              // this wave's k-slice base

  const v8h Z8 = {(half_t)0, (half_t)0, (half_t)0, (half_t)0,
                  (half_t)0, (half_t)0, (half_t)0, (half_t)0};

  // ---- one-time W load: fragments are exactly the MFMA B-operand layout:
  // lane holds W[j = jt*16 + lr][k = ks + kc*32 + lk8 .. +7]
  v8h wreg[WREG_JT][4];
#pragma unroll
  for (int jt = 0; jt < WREG_JT; ++jt)
#pragma unroll
    for (int kc = 0; kc < 4; ++kc)
      wreg[jt][kc] = *(const v8h*)&Waa[(size_t)((WLDS_JT + jt) * 16 + lr) * 512 +
                                       ks + kc * 32 + lk8];
#pragma unroll
  for (int jt = 0; jt < WLDS_JT; ++jt)
#pragma unroll
    for (int kc = 0; kc < 4; ++kc)
      *(v8h*)&Wl[w][jt][kc][l * 8] =
          *(const v8h*)&Waa[(size_t)(jt * 16 + lr) * 512 + ks + kc * 32 + lk8];

  // per-thread persistent cell state for j0 = 2*tid, j0+1
  const int j0 = tid * 2;
  float c0 = 0.f, c1 = 0.f;
  *(v2h*)&hl[j0] = (v2h){(half_t)0, (half_t)0};   // h0 = 0

  const size_t gstride = (size_t)TB_DIM * 512;
  const size_t grow = (size_t)b * 512 + j0;

  // preload gates[t=0]
  v2h gf = *(const v2h*)&gates[grow];
  v2h gi = *(const v2h*)&gates[gstride + grow];
  v2h go = *(const v2h*)&gates[2 * gstride + grow];
  v2h ga = *(const v2h*)&gates[3 * gstride + grow];

  __syncthreads();   // Wl + hl ready

  for (int t = 0; t < T_DIM; ++t) {
    // ---- prefetch next step's gates (independent of h) ----
    const int tn = (t < T_DIM - 1) ? t + 1 : t;
    const size_t gnext = (size_t)tn * (B_DIM * 512) + grow;
    const v2h nf = *(const v2h*)&gates[gnext];
    const v2h ni = *(const v2h*)&gates[gstride + gnext];
    const v2h no_ = *(const v2h*)&gates[2 * gstride + gnext];
    const v2h na = *(const v2h*)&gates[3 * gstride + gnext];

    // ---- split-K GEMV via MFMA (M=16, row 0 valid) ----
    v8h A[4];
#pragma unroll
    for (int kc = 0; kc < 4; ++kc) {
      const v8h hv = *(const v8h*)&hl[ks + kc * 32 + lk8];  // broadcast read
      A[kc] = (lr == 0) ? hv : Z8;
    }
#pragma unroll
    for (int jt = 0; jt < WLDS_JT; ++jt) {
      v4f acc = (v4f){0.f, 0.f, 0.f, 0.f};
#pragma unroll
      for (int kc = 0; kc < 4; ++kc) {
        const v8h bfr = *(const v8h*)&Wl[w][jt][kc][l * 8];
        acc = __builtin_amdgcn_mfma_f32_16x16x32_f16(A[kc], bfr, acc, 0, 0, 0);
      }
      if (l < 16) red[w][jt * 16 + l] = acc[0];   // D: row0 -> lanes 0..15, r=0
    }
#pragma unroll
    for (int jt = 0; jt < WREG_JT; ++jt) {
      v4f acc = (v4f){0.f, 0.f, 0.f, 0.f};
#pragma unroll
      for (int kc = 0; kc < 4; ++kc)
        acc = __builtin_amdgcn_mfma_f32_16x16x32_f16(A[kc], wreg[jt][kc], acc,
                                                     0, 0, 0);
      if (l < 16) red[w][(WLDS_JT + jt) * 16 + l] = acc[0];
    }
    __syncthreads();   // red ready; hl reads done before hl rewrite below

    // ---- reduce across waves + fused gate elementwise ----
    const v2f r0 = *(const v2f*)&red[0][j0];
    const v2f r1 = *(const v2f*)&red[1][j0];
    const v2f r2 = *(const v2f*)&red[2][j0];
    const v2f r3 = *(const v2f*)&red[3][j0];
    const float a0 = r0[0] + r1[0] + r2[0] + r3[0];
    const float a1 = r0[1] + r1[1] + r2[1] + r3[1];

    const float ft0 = sigmoid_f((float)gf[0] + a0);
    const float it0 = sigmoid_f((float)gi[0] + a0);
    const float ot0 = sigmoid_f((float)go[0] + a0);
    const float gg0 = tanh_f((float)ga[0] + a0);
    c0 = ft0 * c0 + it0 * gg0;
    const float h0v = ot0 * tanh_f(c0);

    const float ft1 = sigmoid_f((float)gf[1] + a1);
    const float it1 = sigmoid_f((float)gi[1] + a1);
    const float ot1 = sigmoid_f((float)go[1] + a1);
    const float gg1 = tanh_f((float)ga[1] + a1);
    c1 = ft1 * c1 + it1 * gg1;
    const float h1v = ot1 * tanh_f(c1);

    v2f ov; ov[0] = h0v; ov[1] = h1v;
    *(v2f*)&out[(size_t)t * (B_DIM * H_DIM) + (size_t)b * 512 + j0] = ov;
    v2h hv; hv[0] = (half_t)h0v; hv[1] = (half_t)h1v;
    *(v2h*)&hl[j0] = hv;
    if (t == T_DIM - 1) {
      *(v2f*)&out[(size_t)T_DIM * (B_DIM * H_DIM) + (size_t)b * 512 + j0] = ov;
    }

    gf = nf; gi = ni; go = no_; ga = na;
    __syncthreads();   // hl(t+1) visible; red free for overwrite
  }
}

// ---------------- host ----------------
extern "C" void kernel_launch(void* const* d_in, const int* in_sizes, int n_in,
                              void* d_out, int out_size, void* d_ws, size_t ws_size,
                              hipStream_t stream) {
  const float* X = (const float*)d_in[0];
  const float* Wf = (const float*)d_in[1];
  const float* Wi = (const float*)d_in[2];
  const float* Wo = (const float*)d_in[3];
  const float* Wa = (const float*)d_in[4];
  const float* Waa = (const float*)d_in[5];
  const float* bf = (const float*)d_in[6];
  const float* bi = (const float*)d_in[7];
  const float* bo = (const float*)d_in[8];
  const float* ba = (const float*)d_in[9];
  float* out = (float*)d_out;

  char* ws = (char*)d_ws;
  // workspace layout (bytes)
  half_t* Xh    = (half_t*)(ws + 0);           // 134217728  [TB][512] fp16
  half_t* gates = (half_t*)(ws + 134217728);   // 536870912  [4][TB][512] fp16
  half_t* Wcat  = (half_t*)(ws + 671088640);   // 2097152    [2048][512] fp16
  half_t* Waa16 = (half_t*)(ws + 673185792);   // 524288     [512][512] fp16
  float*  bsum  = (float*)(ws + 673710080);    // 8192       [2048]
  // total: ~642 MB

  k_convX<<<65536, 256, 0, stream>>>((const float4*)X, (v4h*)Xh, 16777216);
  k_convW<<<1280, 256, 0, stream>>>((const float4*)Wf, (const float4*)Wi,
                                    (const float4*)Wo, (const float4*)Wa,
                                    (const float4*)Waa, (v4h*)Wcat, (v4h*)Waa16);
  k_bias<<<8, 256, 0, stream>>>(bf, bi, bo, ba, bsum);

  k_gemm_gates<<<dim3(TB_DIM / 128, NG_DIM / 128), 256, 0, stream>>>(Xh, Wcat, bsum,
                                                                     gates);

  // all 512 recurrent steps: one persistent block per independent batch row
  k_seq<<<256, 256, 0, stream>>>(Waa16, gates, out);
}

// Round 3
// 1830.326 us; speedup vs baseline: 10.0091x; 1.4135x over previous
//
#include <hip/hip_runtime.h>

// ---------------- problem constants ----------------
#define T_DIM 512
#define B_DIM 256
#define D_DIM 512
#define H_DIM 512
#define TB_DIM (T_DIM * B_DIM)   // 131072 (GEMM M)
#define NG_DIM (4 * H_DIM)       // 2048   (GEMM N, 4 gates concat)

typedef _Float16 half_t;
typedef _Float16 v8h __attribute__((ext_vector_type(8)));
typedef _Float16 v4h __attribute__((ext_vector_type(4)));
typedef _Float16 v2h __attribute__((ext_vector_type(2)));
typedef float v4f __attribute__((ext_vector_type(4)));
typedef float v2f __attribute__((ext_vector_type(2)));

// async global->LDS, 16B per lane (global_load_lds_dwordx4)
__device__ __forceinline__ void async_ld16(void* lds, const void* gsrc) {
  __builtin_amdgcn_global_load_lds((__attribute__((address_space(1))) void*)gsrc,
                                   (__attribute__((address_space(3))) void*)lds,
                                   16, 0, 0);
}

__device__ __forceinline__ float sigmoid_f(float x) {
  return 1.0f / (1.0f + __expf(-x));
}
__device__ __forceinline__ float tanh_f(float x) {
  // 1 - 2/(e^{2x}+1); overflow-safe (exp->inf => 1, exp->0 => -1)
  float e = __expf(2.0f * x);
  return 1.0f - 2.0f / (e + 1.0f);
}

// ---------------- converts ----------------
__global__ __launch_bounds__(256) void k_convX(const float4* __restrict__ X,
                                               v4h* __restrict__ Xh, int n4) {
  int i = blockIdx.x * 256 + threadIdx.x;
  if (i < n4) {
    float4 v = X[i];
    v4h o;
    o[0] = (half_t)v.x; o[1] = (half_t)v.y; o[2] = (half_t)v.z; o[3] = (half_t)v.w;
    Xh[i] = o;
  }
}

// builds Wcat16 [2048][512] (f,i,o,a concatenated) and Waa16 [512][512]
__global__ __launch_bounds__(256) void k_convW(const float4* __restrict__ wf,
                                               const float4* __restrict__ wi,
                                               const float4* __restrict__ wo,
                                               const float4* __restrict__ wa,
                                               const float4* __restrict__ waa,
                                               v4h* __restrict__ Wcat,
                                               v4h* __restrict__ Waa16) {
  int idx = blockIdx.x * 256 + threadIdx.x;   // over 5*65536 float4s
  int chunk = idx >> 16;
  int off = idx & 65535;
  const float4* src = (chunk == 0) ? wf : (chunk == 1) ? wi : (chunk == 2) ? wo
                      : (chunk == 3) ? wa : waa;
  float4 v = src[off];
  v4h o;
  o[0] = (half_t)v.x; o[1] = (half_t)v.y; o[2] = (half_t)v.z; o[3] = (half_t)v.w;
  if (chunk < 4) Wcat[chunk * 65536 + off] = o;
  else           Waa16[off] = o;
}

// bsum[col], col = g*512+j: g in {f,i,o}: b_g + b_a ; g==3 (a-gate): b_a
__global__ __launch_bounds__(256) void k_bias(const float* __restrict__ bf,
                                              const float* __restrict__ bi,
                                              const float* __restrict__ bo,
                                              const float* __restrict__ ba,
                                              float* __restrict__ bsum) {
  int i = blockIdx.x * 256 + threadIdx.x;  // 2048
  int g = i >> 9, j = i & 511;
  float v = ba[j];
  if (g == 0) v += bf[j];
  else if (g == 1) v += bi[j];
  else if (g == 2) v += bo[j];
  bsum[i] = v;
}

// ---------------- phase 1: gates = X @ Wcat^T + bsum (fp16 MFMA) ----------------
// 128x128 tile, BK=32, 4 waves each 64x64, m97-style staging. (unchanged)
__global__ __launch_bounds__(256) void k_gemm_gates(
    const half_t* __restrict__ A,    // Xh [TB][512]
    const half_t* __restrict__ Bm,   // Wcat [2048][512]
    const float* __restrict__ bsum,  // [2048]
    half_t* __restrict__ gates) {    // [4][TB][512]
  __shared__ __align__(16) half_t lA[128 * 32];
  __shared__ __align__(16) half_t lB[128 * 32];
  const int tid = threadIdx.x;
  const int l = tid & 63;
  const int w = tid >> 6;
  const int m0 = blockIdx.x * 128;
  const int n0 = blockIdx.y * 128;
  const int wm = (w >> 1) * 64;
  const int wn = (w & 1) * 64;
  const int lr = l & 15;
  const int lk = (l >> 4) * 8;

  v4f acc[4][4];
#pragma unroll
  for (int i = 0; i < 4; i++)
#pragma unroll
    for (int j = 0; j < 4; j++) acc[i][j] = (v4f){0.f, 0.f, 0.f, 0.f};

  const int row_in = tid >> 2;        // 0..63
  const int kc_in = (tid & 3) * 8;    // fp16 elems within BK

  for (int kt = 0; kt < 16; ++kt) {
    const int k0 = kt * 32;
    __syncthreads();
    async_ld16(&lA[tid * 8],        &A[(size_t)(m0 + row_in) * 512 + k0 + kc_in]);
    async_ld16(&lA[2048 + tid * 8], &A[(size_t)(m0 + 64 + row_in) * 512 + k0 + kc_in]);
    async_ld16(&lB[tid * 8],        &Bm[(size_t)(n0 + row_in) * 512 + k0 + kc_in]);
    async_ld16(&lB[2048 + tid * 8], &Bm[(size_t)(n0 + 64 + row_in) * 512 + k0 + kc_in]);
    __syncthreads();

    v8h af[4], bfr[4];
#pragma unroll
    for (int tm = 0; tm < 4; tm++)
      af[tm] = *(const v8h*)&lA[(wm + tm * 16 + lr) * 32 + lk];
#pragma unroll
    for (int tn = 0; tn < 4; tn++)
      bfr[tn] = *(const v8h*)&lB[(wn + tn * 16 + lr) * 32 + lk];
#pragma unroll
    for (int tm = 0; tm < 4; tm++)
#pragma unroll
      for (int tn = 0; tn < 4; tn++)
        acc[tm][tn] = __builtin_amdgcn_mfma_f32_16x16x32_f16(af[tm], bfr[tn],
                                                             acc[tm][tn], 0, 0, 0);
  }

  // epilogue: C/D layout col=lane&15, row=(lane>>4)*4+r  (m89/m91-verified)
#pragma unroll
  for (int tn = 0; tn < 4; tn++) {
    const int col = n0 + wn + tn * 16 + lr;   // virtual col in [0,2048)
    const int g = col >> 9;
    const int j = col & 511;
    const float bias = bsum[col];
    half_t* outg = gates + (size_t)g * TB_DIM * 512 + j;
#pragma unroll
    for (int tm = 0; tm < 4; tm++) {
      const int r0 = m0 + wm + tm * 16 + (l >> 4) * 4;
#pragma unroll
      for (int r = 0; r < 4; r++)
        outg[(size_t)(r0 + r) * 512] = (half_t)(acc[tm][tn][r] + bias);
    }
  }
}

// ---------------- phase 2: one persistent block per batch row ----------------
// Batch rows are INDEPENDENT (a[b,:] depends only on h[b,:]) -> no grid sync.
// 256 blocks (1/CU) x 512 threads (8 waves -> 2 waves/SIMD for TLP).
// Split-K 8-way: wave w owns k in [w*64,(w+1)*64). W_aa weight-stationary:
//   - LDS: j-tiles 0..7   (8 waves x 8 jt x 2 kc x 1KB = 128 KB)
//   - VGPRs: j-tiles 8..31 as MFMA B-fragments (24 jt x 2 kc x 4 = 192 regs)
//     -> fits the 256-VGPR budget of __launch_bounds__(512,2), unlike the
//        previous 368-reg version which the compiler had to re-load from L2.
// Per step: MFMA partials -> red[8][512] f32 -> per-thread (j=tid) reduce +
// fused gate elementwise -> out fp32 + hl fp16. c persistent in registers.
#define WLDS_JT 8
#define WREG_JT 24

__global__ __launch_bounds__(512, 2) void k_seq(
    const half_t* __restrict__ Waa,    // [512][512] fp16
    const half_t* __restrict__ gates,  // [4][TB][512] fp16 (biases folded)
    float* __restrict__ out) {         // [T][256][512] then h_n [256][512]
  __shared__ __align__(16) half_t Wl[8][WLDS_JT][2][512];  // 131072 B
  __shared__ __align__(16) float red[8][512];              //  16384 B
  __shared__ __align__(16) half_t hl[512];                 //   1024 B

  const int tid = threadIdx.x;
  const int l = tid & 63;
  const int w = tid >> 6;              // wave 0..7
  const int lr = l & 15;
  const int lk8 = (l >> 4) * 8;
  const int b = blockIdx.x;            // batch row
  const int ks = w * 64;               // this wave's k-slice base

  const v8h Z8 = {(half_t)0, (half_t)0, (half_t)0, (half_t)0,
                  (half_t)0, (half_t)0, (half_t)0, (half_t)0};

  // ---- one-time W load: fragments in exact MFMA B-operand layout:
  // lane holds W[j = jt*16 + lr][k = ks + kc*32 + lk8 .. +7]
  v8h wreg[WREG_JT][2];
#pragma unroll
  for (int jt = 0; jt < WREG_JT; ++jt)
#pragma unroll
    for (int kc = 0; kc < 2; ++kc)
      wreg[jt][kc] = *(const v8h*)&Waa[(size_t)((WLDS_JT + jt) * 16 + lr) * 512 +
                                       ks + kc * 32 + lk8];
#pragma unroll
  for (int jt = 0; jt < WLDS_JT; ++jt)
#pragma unroll
    for (int kc = 0; kc < 2; ++kc)
      *(v8h*)&Wl[w][jt][kc][l * 8] =
          *(const v8h*)&Waa[(size_t)(jt * 16 + lr) * 512 + ks + kc * 32 + lk8];

  // per-thread persistent cell state for j = tid
  const int j = tid;
  float c = 0.f;
  hl[j] = (half_t)0;   // h0 = 0

  const size_t gstride = (size_t)TB_DIM * 512;
  const size_t grow = (size_t)b * 512 + j;

  // preload gates[t=0]
  float gf = (float)gates[grow];
  float gi = (float)gates[gstride + grow];
  float go = (float)gates[2 * gstride + grow];
  float ga = (float)gates[3 * gstride + grow];

  __syncthreads();   // Wl + hl ready

  for (int t = 0; t < T_DIM; ++t) {
    // ---- prefetch next step's gates (independent of h) ----
    const int tnx = (t < T_DIM - 1) ? t + 1 : t;
    const size_t gnext = (size_t)tnx * (B_DIM * 512) + grow;
    const float nf = (float)gates[gnext];
    const float ni = (float)gates[gstride + gnext];
    const float no_ = (float)gates[2 * gstride + gnext];
    const float na = (float)gates[3 * gstride + gnext];

    // ---- split-K GEMV via MFMA (M=16, row 0 valid) ----
    v8h A[2];
#pragma unroll
    for (int kc = 0; kc < 2; ++kc) {
      const v8h hv = *(const v8h*)&hl[ks + kc * 32 + lk8];  // broadcast read
      A[kc] = (lr == 0) ? hv : Z8;
    }
    if (t > 0) {                                  // h0 == 0 -> a == 0
#pragma unroll
      for (int jt = 0; jt < WLDS_JT; ++jt) {
        v4f acc = (v4f){0.f, 0.f, 0.f, 0.f};
#pragma unroll
        for (int kc = 0; kc < 2; ++kc) {
          const v8h bfr = *(const v8h*)&Wl[w][jt][kc][l * 8];
          acc = __builtin_amdgcn_mfma_f32_16x16x32_f16(A[kc], bfr, acc, 0, 0, 0);
        }
        if (l < 16) red[w][jt * 16 + l] = acc[0];  // D row0 -> lanes 0..15, r=0
      }
#pragma unroll
      for (int jt = 0; jt < WREG_JT; ++jt) {
        v4f acc = (v4f){0.f, 0.f, 0.f, 0.f};
#pragma unroll
        for (int kc = 0; kc < 2; ++kc)
          acc = __builtin_amdgcn_mfma_f32_16x16x32_f16(A[kc], wreg[jt][kc], acc,
                                                       0, 0, 0);
        if (l < 16) red[w][(WLDS_JT + jt) * 16 + l] = acc[0];
      }
    } else {
#pragma unroll
      for (int jt = 0; jt < 32; ++jt)
        if (l < 16) red[w][jt * 16 + l] = 0.f;
    }
    __syncthreads();   // red ready; hl reads done before hl rewrite below

    // ---- reduce across 8 waves + fused gate elementwise (thread j = tid) ----
    // red[w][j]: bank j%32, lanes l and l+32 alias 2-way (free)
    const float a = red[0][j] + red[1][j] + red[2][j] + red[3][j] +
                    red[4][j] + red[5][j] + red[6][j] + red[7][j];

    const float ft = sigmoid_f(gf + a);
    const float it = sigmoid_f(gi + a);
    const float ot = sigmoid_f(go + a);
    const float gg = tanh_f(ga + a);
    c = ft * c + it * gg;
    const float hv = ot * tanh_f(c);

    out[(size_t)t * (B_DIM * H_DIM) + (size_t)b * 512 + j] = hv;
    hl[j] = (half_t)hv;
    if (t == T_DIM - 1) {
      out[(size_t)T_DIM * (B_DIM * H_DIM) + (size_t)b * 512 + j] = hv;
    }

    gf = nf; gi = ni; go = no_; ga = na;
    __syncthreads();   // hl(t+1) visible; red free for overwrite
  }
}

// ---------------- host ----------------
extern "C" void kernel_launch(void* const* d_in, const int* in_sizes, int n_in,
                              void* d_out, int out_size, void* d_ws, size_t ws_size,
                              hipStream_t stream) {
  const float* X = (const float*)d_in[0];
  const float* Wf = (const float*)d_in[1];
  const float* Wi = (const float*)d_in[2];
  const float* Wo = (const float*)d_in[3];
  const float* Wa = (const float*)d_in[4];
  const float* Waa = (const float*)d_in[5];
  const float* bf = (const float*)d_in[6];
  const float* bi = (const float*)d_in[7];
  const float* bo = (const float*)d_in[8];
  const float* ba = (const float*)d_in[9];
  float* out = (float*)d_out;

  char* ws = (char*)d_ws;
  // workspace layout (bytes)
  half_t* Xh    = (half_t*)(ws + 0);           // 134217728  [TB][512] fp16
  half_t* gates = (half_t*)(ws + 134217728);   // 536870912  [4][TB][512] fp16
  half_t* Wcat  = (half_t*)(ws + 671088640);   // 2097152    [2048][512] fp16
  half_t* Waa16 = (half_t*)(ws + 673185792);   // 524288     [512][512] fp16
  float*  bsum  = (float*)(ws + 673710080);    // 8192       [2048]
  // total: ~642 MB

  k_convX<<<65536, 256, 0, stream>>>((const float4*)X, (v4h*)Xh, 16777216);
  k_convW<<<1280, 256, 0, stream>>>((const float4*)Wf, (const float4*)Wi,
                                    (const float4*)Wo, (const float4*)Wa,
                                    (const float4*)Waa, (v4h*)Wcat, (v4h*)Waa16);
  k_bias<<<8, 256, 0, stream>>>(bf, bi, bo, ba, bsum);

  k_gemm_gates<<<dim3(TB_DIM / 128, NG_DIM / 128), 256, 0, stream>>>(Xh, Wcat, bsum,
                                                                     gates);

  // all 512 recurrent steps: one persistent block per independent batch row
  k_seq<<<256, 512, 0, stream>>>(Waa16, gates, out);
}